// Round 1
// baseline (498.969 us; speedup 1.0000x reference)
//
#include <hip/hip_runtime.h>
#include <hip/hip_bf16.h>

typedef short bf16x8 __attribute__((ext_vector_type(8)));
typedef short short4v __attribute__((ext_vector_type(4)));
typedef float f32x4 __attribute__((ext_vector_type(4)));

__device__ __forceinline__ short f2b(float f) {
  __hip_bfloat16 h = __float2bfloat16(f);
  union { __hip_bfloat16 h; short s; } u; u.h = h; return u.s;
}

// ---------------- fp32 -> bf16 elementwise (x) ----------------
__global__ __launch_bounds__(256) void cvt_kernel(const float* __restrict__ in,
                                                  short* __restrict__ out, int n4) {
  const int i = blockIdx.x * 256 + threadIdx.x;
  if (i >= n4) return;
  const float4 v = ((const float4*)in)[i];
  short4v o;
  o[0] = f2b(v.x); o[1] = f2b(v.y); o[2] = f2b(v.z); o[3] = f2b(v.w);
  ((short4v*)out)[i] = o;
}

// ---------------- fp32 [R][Cn] -> bf16 transposed [Cn][R] ----------------
__global__ __launch_bounds__(256) void tcvt_kernel(const float* __restrict__ in,
                                                   short* __restrict__ out, int R, int Cn) {
  __shared__ float t[32][33];
  const int tx = threadIdx.x, ty = threadIdx.y;
  const int c0 = blockIdx.x * 32, r0 = blockIdx.y * 32;
#pragma unroll
  for (int yy = 0; yy < 32; yy += 8)
    t[ty + yy][tx] = in[(size_t)(r0 + ty + yy) * Cn + (c0 + tx)];
  __syncthreads();
#pragma unroll
  for (int yy = 0; yy < 32; yy += 8)
    out[(size_t)(c0 + ty + yy) * R + (r0 + tx)] = f2b(t[tx][ty + yy]);
}

// ---------------- C[M,N] = A[M,K] * Bt[N,K]^T  (bf16 in, OutT out) ----------------
// 128x128 tile, BK=32, 256 threads = 4 waves, each wave 64x64 via 4x4 of 16x16x32 MFMA.
template <typename OutT>
__global__ __launch_bounds__(256) void gemm_bt_kernel(const short* __restrict__ A,
                                                      const short* __restrict__ Bt,
                                                      OutT* __restrict__ C,
                                                      int M, int N, int K) {
  __shared__ short As[128 * 32];
  __shared__ short Bs[128 * 32];
  const int tid = threadIdx.x;
  const int lane = tid & 63, wave = tid >> 6;
  const int quad = lane >> 4, l16 = lane & 15;
  const int m0 = blockIdx.y * 128, n0 = blockIdx.x * 128;
  const int wm = (wave >> 1) * 64, wn = (wave & 1) * 64;

  f32x4 acc[4][4] = {};

  const int srow = tid >> 1;         // 0..127
  const int skcol = (tid & 1) * 16;  // 0 or 16
  const short* aptr = A + (size_t)(m0 + srow) * K + skcol;
  const short* bptr = Bt + (size_t)(n0 + srow) * K + skcol;
  short* asd = &As[srow * 32 + skcol];
  short* bsd = &Bs[srow * 32 + skcol];

  for (int kt = 0; kt < K; kt += 32) {
    __syncthreads();
    *(bf16x8*)asd = *(const bf16x8*)aptr;
    *(bf16x8*)(asd + 8) = *(const bf16x8*)(aptr + 8);
    *(bf16x8*)bsd = *(const bf16x8*)bptr;
    *(bf16x8*)(bsd + 8) = *(const bf16x8*)(bptr + 8);
    aptr += 32; bptr += 32;
    __syncthreads();
    bf16x8 af[4], bfr[4];
#pragma unroll
    for (int mt = 0; mt < 4; mt++)
      af[mt] = *(const bf16x8*)&As[(wm + mt * 16 + l16) * 32 + quad * 8];
#pragma unroll
    for (int nt = 0; nt < 4; nt++)
      bfr[nt] = *(const bf16x8*)&Bs[(wn + nt * 16 + l16) * 32 + quad * 8];
#pragma unroll
    for (int mt = 0; mt < 4; mt++)
#pragma unroll
      for (int nt = 0; nt < 4; nt++)
        acc[mt][nt] = __builtin_amdgcn_mfma_f32_16x16x32_bf16(af[mt], bfr[nt], acc[mt][nt], 0, 0, 0);
  }

#pragma unroll
  for (int mt = 0; mt < 4; mt++)
#pragma unroll
    for (int nt = 0; nt < 4; nt++) {
      const int col = n0 + wn + nt * 16 + l16;
#pragma unroll
      for (int r = 0; r < 4; r++) {
        const int row = m0 + wm + mt * 16 + quad * 4 + r;
        const float v = acc[mt][nt][r];
        if constexpr (sizeof(OutT) == 4) {
          C[(size_t)row * N + col] = v;
        } else {
          C[(size_t)row * N + col] = f2b(v);
        }
      }
    }
}

// ---------------- causal flash attention ----------------
// grid: (T/64, B*H), block 256. Each block: one (b,h), 64 q-rows; each wave: 16 q-rows.
__global__ __launch_bounds__(256) void attn_kernel(const short* __restrict__ qkv,
                                                   short* __restrict__ y) {
  constexpr int T = 2048, C3 = 3072, Cc = 1024, HD = 64;
  const int bh = blockIdx.y, b = bh >> 4, h = bh & 15;
  const int qtile = blockIdx.x;
  const int q0 = qtile * 64;
  const int tid = threadIdx.x, lane = tid & 63, wave = tid >> 6;
  const int quad = lane >> 4, l16 = lane & 15;

  __shared__ short Ks[64 * 64];      // [kv][d]
  __shared__ short Vt[64 * 72];      // [d][kv], pad +8
  __shared__ short Ps[4][16 * 72];   // per-wave P [q][kv], pad +8

  const size_t base = (size_t)b * T * C3;
  const int qcol = h * HD, kcol = Cc + h * HD, vcol = 2 * Cc + h * HD;

  // Q fragments for this wave's 16 rows (A-layout: m=l16, k=quad*8+j)
  bf16x8 qf[2];
  {
    const short* qp = qkv + base + (size_t)(q0 + wave * 16 + l16) * C3 + qcol + quad * 8;
    qf[0] = *(const bf16x8*)qp;
    qf[1] = *(const bf16x8*)(qp + 32);
  }

  float m_r[4], l_r[4];
  f32x4 o[4] = {};
#pragma unroll
  for (int r = 0; r < 4; r++) { m_r[r] = -INFINITY; l_r[r] = 0.f; }

  const int srow = tid >> 2;        // 0..63
  const int sc0 = (tid & 3) * 16;   // 0,16,32,48

  for (int j = 0; j <= qtile; j++) {
    const int kv0 = j * 64;
    __syncthreads();
    {
      const short* kp = qkv + base + (size_t)(kv0 + srow) * C3 + kcol + sc0;
      *(bf16x8*)&Ks[srow * 64 + sc0] = *(const bf16x8*)kp;
      *(bf16x8*)&Ks[srow * 64 + sc0 + 8] = *(const bf16x8*)(kp + 8);
      const short* vp = qkv + base + (size_t)(kv0 + srow) * C3 + vcol + sc0;
      bf16x8 v0 = *(const bf16x8*)vp;
      bf16x8 v1 = *(const bf16x8*)(vp + 8);
#pragma unroll
      for (int jj = 0; jj < 8; jj++) {
        Vt[(sc0 + jj) * 72 + srow] = v0[jj];
        Vt[(sc0 + 8 + jj) * 72 + srow] = v1[jj];
      }
    }
    __syncthreads();

    // S = Q * K^T  (16 x 64 per wave)
    f32x4 s[4];
#pragma unroll
    for (int nt = 0; nt < 4; nt++) {
      bf16x8 b0 = *(const bf16x8*)&Ks[(nt * 16 + l16) * 64 + quad * 8];
      bf16x8 b1 = *(const bf16x8*)&Ks[(nt * 16 + l16) * 64 + 32 + quad * 8];
      f32x4 a = {};
      a = __builtin_amdgcn_mfma_f32_16x16x32_bf16(qf[0], b0, a, 0, 0, 0);
      a = __builtin_amdgcn_mfma_f32_16x16x32_bf16(qf[1], b1, a, 0, 0, 0);
      s[nt] = a;
    }

    const bool diag = (j == qtile);
    float rowmax[4];
#pragma unroll
    for (int r = 0; r < 4; r++) rowmax[r] = -INFINITY;
#pragma unroll
    for (int nt = 0; nt < 4; nt++)
#pragma unroll
      for (int r = 0; r < 4; r++) {
        float v = s[nt][r] * 0.125f;  // 1/sqrt(64)
        if (diag) {
          const int row_l = wave * 16 + quad * 4 + r;
          const int col_l = nt * 16 + l16;
          if (col_l > row_l) v = -INFINITY;
        }
        s[nt][r] = v;
        rowmax[r] = fmaxf(rowmax[r], v);
      }
#pragma unroll
    for (int r = 0; r < 4; r++)
#pragma unroll
      for (int off = 1; off < 16; off <<= 1)
        rowmax[r] = fmaxf(rowmax[r], __shfl_xor(rowmax[r], off));

    float alpha[4], rsum[4];
#pragma unroll
    for (int r = 0; r < 4; r++) {
      const float mn = fmaxf(m_r[r], rowmax[r]);
      alpha[r] = __expf(m_r[r] - mn);
      m_r[r] = mn;
      rsum[r] = 0.f;
    }
#pragma unroll
    for (int nt = 0; nt < 4; nt++)
#pragma unroll
      for (int r = 0; r < 4; r++) {
        const float p = __expf(s[nt][r] - m_r[r]);
        s[nt][r] = p;
        rsum[r] += p;
      }
#pragma unroll
    for (int r = 0; r < 4; r++) {
#pragma unroll
      for (int off = 1; off < 16; off <<= 1)
        rsum[r] += __shfl_xor(rsum[r], off);
      l_r[r] = l_r[r] * alpha[r] + rsum[r];
    }
#pragma unroll
    for (int nt = 0; nt < 4; nt++)
#pragma unroll
      for (int r = 0; r < 4; r++)
        o[nt][r] *= alpha[r];

    // P: C-layout regs -> LDS -> A-layout frags
#pragma unroll
    for (int nt = 0; nt < 4; nt++)
#pragma unroll
      for (int r = 0; r < 4; r++)
        Ps[wave][(quad * 4 + r) * 72 + nt * 16 + l16] = f2b(s[nt][r]);
    __syncthreads();

#pragma unroll
    for (int ks = 0; ks < 2; ks++) {
      bf16x8 pa = *(const bf16x8*)&Ps[wave][l16 * 72 + ks * 32 + quad * 8];
#pragma unroll
      for (int nt = 0; nt < 4; nt++) {
        bf16x8 vb = *(const bf16x8*)&Vt[(nt * 16 + l16) * 72 + ks * 32 + quad * 8];
        o[nt] = __builtin_amdgcn_mfma_f32_16x16x32_bf16(pa, vb, o[nt], 0, 0, 0);
      }
    }
  }

#pragma unroll
  for (int nt = 0; nt < 4; nt++)
#pragma unroll
    for (int r = 0; r < 4; r++) {
      const int row_g = q0 + wave * 16 + quad * 4 + r;
      y[(size_t)(b * T + row_g) * Cc + h * HD + nt * 16 + l16] = f2b(o[nt][r] / l_r[r]);
    }
}

extern "C" void kernel_launch(void* const* d_in, const int* in_sizes, int n_in,
                              void* d_out, int out_size, void* d_ws, size_t ws_size,
                              hipStream_t stream) {
  constexpr int B = 4, T = 2048, C = 1024;
  constexpr int M = B * T;          // 8192
  constexpr int N1 = 3 * C;         // 3072
  const float* x      = (const float*)d_in[0];
  const float* w_attn = (const float*)d_in[1];
  const float* w_proj = (const float*)d_in[2];
  float* out = (float*)d_out;

  char* ws = (char*)d_ws;
  // workspace layout (bf16 = 2B each)
  short* xb   = (short*)(ws + 0);                       // 8192*1024   = 16 MB
  short* waT  = (short*)(ws + 16777216);                // 3072*1024   =  6 MB
  short* wpT  = (short*)(ws + 23068672);                // 1024*1024   =  2 MB
  short* qkvb = (short*)(ws + 25165824);                // 8192*3072   = 48 MB
  short* yb   = (short*)(ws + 75497472);                // 8192*1024   = 16 MB

  // 1) convert x to bf16
  cvt_kernel<<<(M * C / 4 + 255) / 256, 256, 0, stream>>>(x, xb, M * C / 4);
  // 2) transpose+convert weights: w_attn [C][3C] -> [3C][C]; w_proj [C][C] -> [C][C]
  tcvt_kernel<<<dim3(N1 / 32, C / 32), dim3(32, 8), 0, stream>>>(w_attn, waT, C, N1);
  tcvt_kernel<<<dim3(C / 32, C / 32), dim3(32, 8), 0, stream>>>(w_proj, wpT, C, C);
  // 3) qkv = x @ w_attn   [8192,3072]
  gemm_bt_kernel<short><<<dim3(N1 / 128, M / 128), 256, 0, stream>>>(xb, waT, qkvb, M, N1, C);
  // 4) flash attention -> yb [8192,1024]
  attn_kernel<<<dim3(T / 64, B * 16), 256, 0, stream>>>(qkvb, yb);
  // 5) out = yb @ w_proj  [8192,1024] fp32
  gemm_bt_kernel<float><<<dim3(C / 128, M / 128), 256, 0, stream>>>(yb, wpT, out, M, C, C);
}

// Round 3
// 357.813 us; speedup vs baseline: 1.3945x; 1.3945x over previous
//
#include <hip/hip_runtime.h>
#include <hip/hip_bf16.h>

typedef short bf16x8 __attribute__((ext_vector_type(8)));
typedef short short4v __attribute__((ext_vector_type(4)));
typedef float f32x4 __attribute__((ext_vector_type(4)));

__device__ __forceinline__ short f2b(float f) {
  __hip_bfloat16 h = __float2bfloat16(f);
  union { __hip_bfloat16 h; short s; } u; u.h = h; return u.s;
}

// async 16B global -> LDS (lane i lands at lds_base + i*16; lds ptr must be wave-uniform)
__device__ __forceinline__ void async_copy16(const short* g, short* l) {
  __builtin_amdgcn_global_load_lds((const __attribute__((address_space(1))) void*)g,
                                   (__attribute__((address_space(3))) void*)l, 16, 0, 0);
}

// ---------------- fp32 -> bf16 elementwise (x) ----------------
__global__ __launch_bounds__(256) void cvt_kernel(const float* __restrict__ in,
                                                  short* __restrict__ out, int n4) {
  const int i = blockIdx.x * 256 + threadIdx.x;
  if (i >= n4) return;
  const float4 v = ((const float4*)in)[i];
  short4v o;
  o[0] = f2b(v.x); o[1] = f2b(v.y); o[2] = f2b(v.z); o[3] = f2b(v.w);
  ((short4v*)out)[i] = o;
}

// ---------------- fp32 [R][Cn] -> bf16 transposed [Cn][R] ----------------
// Output rows with index < qscale_rows get multiplied by qscale
// (folds softmax 1/sqrt(HD)*log2(e) into the Q columns of w_attn).
__global__ __launch_bounds__(256) void tcvt_kernel(const float* __restrict__ in,
                                                   short* __restrict__ out, int R, int Cn,
                                                   int qscale_rows, float qscale) {
  __shared__ float t[32][33];
  const int tx = threadIdx.x, ty = threadIdx.y;
  const int c0 = blockIdx.x * 32, r0 = blockIdx.y * 32;
#pragma unroll
  for (int yy = 0; yy < 32; yy += 8)
    t[ty + yy][tx] = in[(size_t)(r0 + ty + yy) * Cn + (c0 + tx)];
  __syncthreads();
#pragma unroll
  for (int yy = 0; yy < 32; yy += 8) {
    const int orow = c0 + ty + yy;
    float v = t[tx][ty + yy];
    if (orow < qscale_rows) v *= qscale;
    out[(size_t)orow * R + (r0 + tx)] = f2b(v);
  }
}

// ---------------- C[M,N] = A[M,K] * Bt[N,K]^T  (bf16 in, OutT out) ----------------
// 128x128 tile, BK=32, 256 threads = 4 waves, each wave 64x64 via 4x4 of 16x16x32 MFMA.
// Staging via global_load_lds width=16 (m97 pattern).
template <typename OutT>
__global__ __launch_bounds__(256) void gemm_bt_kernel(const short* __restrict__ A,
                                                      const short* __restrict__ Bt,
                                                      OutT* __restrict__ C,
                                                      int M, int N, int K) {
  __shared__ short As[128 * 32];
  __shared__ short Bs[128 * 32];
  const int tid = threadIdx.x;
  const int lane = tid & 63, wave = tid >> 6;
  const int quad = lane >> 4, l16 = lane & 15;
  const int m0 = blockIdx.y * 128, n0 = blockIdx.x * 128;
  const int wm = (wave >> 1) * 64, wn = (wave & 1) * 64;

  f32x4 acc[4][4] = {};

  // global_load_lds staging: wave w, instr t in {0,1}:
  //   lds byte base = (w*2+t)*1024 (uniform); lane i -> row w*32+t*16+i/4, kcol (i&3)*8
  const int lrow = wave * 32 + (lane >> 2);
  const int lcol = (lane & 3) * 8;
  const short* ga0 = A + (size_t)(m0 + lrow) * K + lcol;
  const short* ga1 = A + (size_t)(m0 + lrow + 16) * K + lcol;
  const short* gb0 = Bt + (size_t)(n0 + lrow) * K + lcol;
  const short* gb1 = Bt + (size_t)(n0 + lrow + 16) * K + lcol;
  short* la0 = &As[(wave * 2 + 0) * 512];
  short* la1 = &As[(wave * 2 + 1) * 512];
  short* lb0 = &Bs[(wave * 2 + 0) * 512];
  short* lb1 = &Bs[(wave * 2 + 1) * 512];

  for (int kt = 0; kt < K; kt += 32) {
    __syncthreads();                 // prev iter's LDS reads done
    async_copy16(ga0 + kt, la0);
    async_copy16(ga1 + kt, la1);
    async_copy16(gb0 + kt, lb0);
    async_copy16(gb1 + kt, lb1);
    __syncthreads();                 // drains vmcnt(0): staged data visible
    bf16x8 af[4], bfr[4];
#pragma unroll
    for (int mt = 0; mt < 4; mt++)
      af[mt] = *(const bf16x8*)&As[(wm + mt * 16 + l16) * 32 + quad * 8];
#pragma unroll
    for (int nt = 0; nt < 4; nt++)
      bfr[nt] = *(const bf16x8*)&Bs[(wn + nt * 16 + l16) * 32 + quad * 8];
#pragma unroll
    for (int mt = 0; mt < 4; mt++)
#pragma unroll
      for (int nt = 0; nt < 4; nt++)
        acc[mt][nt] = __builtin_amdgcn_mfma_f32_16x16x32_bf16(af[mt], bfr[nt], acc[mt][nt], 0, 0, 0);
  }

#pragma unroll
  for (int mt = 0; mt < 4; mt++)
#pragma unroll
    for (int nt = 0; nt < 4; nt++) {
      const int col = n0 + wn + nt * 16 + l16;
#pragma unroll
      for (int r = 0; r < 4; r++) {
        const int row = m0 + wm + mt * 16 + quad * 4 + r;
        const float v = acc[mt][nt][r];
        if constexpr (sizeof(OutT) == 4) {
          C[(size_t)row * N + col] = v;
        } else {
          C[(size_t)row * N + col] = f2b(v);
        }
      }
    }
}

// ---------------- causal flash attention ----------------
// grid: (16, B*H), block 256. Block x handles qtiles {31-x, x} (uniform 33 KV-iters).
// Q pre-scaled by 1/sqrt(HD)*log2(e) (folded into w_attn); softmax in exp2 domain.
__global__ __launch_bounds__(256) void attn_kernel(const short* __restrict__ qkv,
                                                   short* __restrict__ y) {
  constexpr int T = 2048, C3 = 3072, Cc = 1024, HD = 64, NQ = 32;
  const int bh = blockIdx.y, b = bh >> 4, h = bh & 15;
  const int tid = threadIdx.x, lane = tid & 63, wave = tid >> 6;
  const int quad = lane >> 4, l16 = lane & 15;

  __shared__ short Ks[64 * 64];      // [kv][d]
  __shared__ short Vt[64 * 72];      // [d][kv], pad +8
  __shared__ short Ps[4][16 * 72];   // per-wave P [q][kv], pad +8

  const size_t base = (size_t)b * T * C3;
  const int qcol = h * HD, kcol = Cc + h * HD, vcol = 2 * Cc + h * HD;
  const int srow = tid >> 2;        // 0..63
  const int sc0 = (tid & 3) * 16;   // 0,16,32,48

  for (int half = 0; half < 2; half++) {
    const int qtile = half ? blockIdx.x : (NQ - 1 - blockIdx.x);
    const int q0 = qtile * 64;

    // Q fragments for this wave's 16 rows (A-layout: m=l16, k=quad*8+j)
    bf16x8 qf[2];
    {
      const short* qp = qkv + base + (size_t)(q0 + wave * 16 + l16) * C3 + qcol + quad * 8;
      qf[0] = *(const bf16x8*)qp;
      qf[1] = *(const bf16x8*)(qp + 32);
    }

    float m_r[4], l_r[4];
    f32x4 o[4] = {};
#pragma unroll
    for (int r = 0; r < 4; r++) { m_r[r] = -INFINITY; l_r[r] = 0.f; }

    for (int j = 0; j <= qtile; j++) {
      const int kv0 = j * 64;
      __syncthreads();   // all waves done reading Ks/Vt from previous iter
      {
        const short* kp = qkv + base + (size_t)(kv0 + srow) * C3 + kcol + sc0;
        *(bf16x8*)&Ks[srow * 64 + sc0] = *(const bf16x8*)kp;
        *(bf16x8*)&Ks[srow * 64 + sc0 + 8] = *(const bf16x8*)(kp + 8);
        const short* vp = qkv + base + (size_t)(kv0 + srow) * C3 + vcol + sc0;
        bf16x8 v0 = *(const bf16x8*)vp;
        bf16x8 v1 = *(const bf16x8*)(vp + 8);
#pragma unroll
        for (int jj = 0; jj < 8; jj++) {
          Vt[(sc0 + jj) * 72 + srow] = v0[jj];
          Vt[(sc0 + 8 + jj) * 72 + srow] = v1[jj];
        }
      }
      __syncthreads();

      // S = Q * K^T  (16 x 64 per wave), already in log2 units
      f32x4 s[4];
#pragma unroll
      for (int nt = 0; nt < 4; nt++) {
        bf16x8 b0 = *(const bf16x8*)&Ks[(nt * 16 + l16) * 64 + quad * 8];
        bf16x8 b1 = *(const bf16x8*)&Ks[(nt * 16 + l16) * 64 + 32 + quad * 8];
        f32x4 a = {};
        a = __builtin_amdgcn_mfma_f32_16x16x32_bf16(qf[0], b0, a, 0, 0, 0);
        a = __builtin_amdgcn_mfma_f32_16x16x32_bf16(qf[1], b1, a, 0, 0, 0);
        s[nt] = a;
      }

      const bool diag = (j == qtile);
      float rowmax[4];
#pragma unroll
      for (int r = 0; r < 4; r++) rowmax[r] = -INFINITY;
      if (diag) {
#pragma unroll
        for (int nt = 0; nt < 4; nt++)
#pragma unroll
          for (int r = 0; r < 4; r++) {
            const int row_l = wave * 16 + quad * 4 + r;
            const int col_l = nt * 16 + l16;
            if (col_l > row_l) s[nt][r] = -INFINITY;
            rowmax[r] = fmaxf(rowmax[r], s[nt][r]);
          }
      } else {
#pragma unroll
        for (int nt = 0; nt < 4; nt++)
#pragma unroll
          for (int r = 0; r < 4; r++)
            rowmax[r] = fmaxf(rowmax[r], s[nt][r]);
      }
#pragma unroll
      for (int r = 0; r < 4; r++)
#pragma unroll
        for (int off = 1; off < 16; off <<= 1)
          rowmax[r] = fmaxf(rowmax[r], __shfl_xor(rowmax[r], off));

      float alpha[4], rsum[4];
#pragma unroll
      for (int r = 0; r < 4; r++) {
        const float mn = fmaxf(m_r[r], rowmax[r]);
        alpha[r] = __builtin_amdgcn_exp2f(m_r[r] - mn);
        m_r[r] = mn;
        rsum[r] = 0.f;
      }
#pragma unroll
      for (int nt = 0; nt < 4; nt++)
#pragma unroll
        for (int r = 0; r < 4; r++) {
          const float p = __builtin_amdgcn_exp2f(s[nt][r] - m_r[r]);
          s[nt][r] = p;
          rsum[r] += p;
        }
#pragma unroll
      for (int r = 0; r < 4; r++) {
#pragma unroll
        for (int off = 1; off < 16; off <<= 1)
          rsum[r] += __shfl_xor(rsum[r], off);
        l_r[r] = l_r[r] * alpha[r] + rsum[r];
      }
#pragma unroll
      for (int nt = 0; nt < 4; nt++)
#pragma unroll
        for (int r = 0; r < 4; r++)
          o[nt][r] *= alpha[r];

      // P: C-layout regs -> LDS -> A-layout frags. Ps[wave] is wave-private, but
      // LDS ops complete out of order (lgkmcnt OoO): force the writes to land
      // before the b128 reads. Wave-local wait, no cross-wave barrier needed.
#pragma unroll
      for (int nt = 0; nt < 4; nt++)
#pragma unroll
        for (int r = 0; r < 4; r++)
          Ps[wave][(quad * 4 + r) * 72 + nt * 16 + l16] = f2b(s[nt][r]);
      asm volatile("s_waitcnt lgkmcnt(0)" ::: "memory");

#pragma unroll
      for (int ks = 0; ks < 2; ks++) {
        bf16x8 pa = *(const bf16x8*)&Ps[wave][l16 * 72 + ks * 32 + quad * 8];
#pragma unroll
        for (int nt = 0; nt < 4; nt++) {
          bf16x8 vb = *(const bf16x8*)&Vt[(nt * 16 + l16) * 72 + ks * 32 + quad * 8];
          o[nt] = __builtin_amdgcn_mfma_f32_16x16x32_bf16(pa, vb, o[nt], 0, 0, 0);
        }
      }
    }

#pragma unroll
    for (int nt = 0; nt < 4; nt++)
#pragma unroll
      for (int r = 0; r < 4; r++) {
        const int row_g = q0 + wave * 16 + quad * 4 + r;
        y[(size_t)(b * T + row_g) * Cc + h * HD + nt * 16 + l16] = f2b(o[nt][r] / l_r[r]);
      }
  }
}

extern "C" void kernel_launch(void* const* d_in, const int* in_sizes, int n_in,
                              void* d_out, int out_size, void* d_ws, size_t ws_size,
                              hipStream_t stream) {
  constexpr int B = 4, T = 2048, C = 1024;
  constexpr int M = B * T;          // 8192
  constexpr int N1 = 3 * C;         // 3072
  const float* x      = (const float*)d_in[0];
  const float* w_attn = (const float*)d_in[1];
  const float* w_proj = (const float*)d_in[2];
  float* out = (float*)d_out;

  char* ws = (char*)d_ws;
  short* xb   = (short*)(ws + 0);                       // 8192*1024   = 16 MB
  short* waT  = (short*)(ws + 16777216);                // 3072*1024   =  6 MB
  short* wpT  = (short*)(ws + 23068672);                // 1024*1024   =  2 MB
  short* qkvb = (short*)(ws + 25165824);                // 8192*3072   = 48 MB
  short* yb   = (short*)(ws + 75497472);                // 8192*1024   = 16 MB

  // softmax scale folded into Q columns: 1/sqrt(64) * log2(e)
  const float qscale = 0.125f * 1.44269504088896340736f;

  cvt_kernel<<<(M * C / 4 + 255) / 256, 256, 0, stream>>>(x, xb, M * C / 4);
  tcvt_kernel<<<dim3(N1 / 32, C / 32), dim3(32, 8), 0, stream>>>(w_attn, waT, C, N1, C, qscale);
  tcvt_kernel<<<dim3(C / 32, C / 32), dim3(32, 8), 0, stream>>>(w_proj, wpT, C, C, 0, 1.0f);
  gemm_bt_kernel<short><<<dim3(N1 / 128, M / 128), 256, 0, stream>>>(xb, waT, qkvb, M, N1, C);
  attn_kernel<<<dim3(16, B * 16), 256, 0, stream>>>(qkvb, yb);
  gemm_bt_kernel<float><<<dim3(C / 128, M / 128), 256, 0, stream>>>(yb, wpT, out, M, C, C);
}

// Round 4
// 313.872 us; speedup vs baseline: 1.5897x; 1.1400x over previous
//
#include <hip/hip_runtime.h>
#include <hip/hip_bf16.h>

typedef short bf16x8 __attribute__((ext_vector_type(8)));
typedef short short4v __attribute__((ext_vector_type(4)));
typedef float f32x4 __attribute__((ext_vector_type(4)));

__device__ __forceinline__ short f2b(float f) {
  __hip_bfloat16 h = __float2bfloat16(f);
  union { __hip_bfloat16 h; short s; } u; u.h = h; return u.s;
}

// async 16B global -> LDS (lane i lands at lds_base + i*16; lds ptr must be wave-uniform)
__device__ __forceinline__ void async_copy16(const short* g, short* l) {
  __builtin_amdgcn_global_load_lds((const __attribute__((address_space(1))) void*)g,
                                   (__attribute__((address_space(3))) void*)l, 16, 0, 0);
}

// ---------------- fp32 -> bf16 elementwise (x) ----------------
__global__ __launch_bounds__(256) void cvt_kernel(const float* __restrict__ in,
                                                  short* __restrict__ out, int n4) {
  const int i = blockIdx.x * 256 + threadIdx.x;
  if (i >= n4) return;
  const float4 v = ((const float4*)in)[i];
  short4v o;
  o[0] = f2b(v.x); o[1] = f2b(v.y); o[2] = f2b(v.z); o[3] = f2b(v.w);
  ((short4v*)out)[i] = o;
}

// ---------------- fp32 [R][Cn] -> bf16 transposed [Cn][R] ----------------
// Output rows with index < qscale_rows get multiplied by qscale
// (folds softmax 1/sqrt(HD)*log2(e) into the Q columns of w_attn).
__global__ __launch_bounds__(256) void tcvt_kernel(const float* __restrict__ in,
                                                   short* __restrict__ out, int R, int Cn,
                                                   int qscale_rows, float qscale) {
  __shared__ float t[32][33];
  const int tx = threadIdx.x, ty = threadIdx.y;
  const int c0 = blockIdx.x * 32, r0 = blockIdx.y * 32;
#pragma unroll
  for (int yy = 0; yy < 32; yy += 8)
    t[ty + yy][tx] = in[(size_t)(r0 + ty + yy) * Cn + (c0 + tx)];
  __syncthreads();
#pragma unroll
  for (int yy = 0; yy < 32; yy += 8) {
    const int orow = c0 + ty + yy;
    float v = t[tx][ty + yy];
    if (orow < qscale_rows) v *= qscale;
    out[(size_t)orow * R + (r0 + tx)] = f2b(v);
  }
}

// ---------------- C[M,N] = A[M,K] * Bt[N,K]^T  (bf16 in, OutT out) ----------------
// 128x128 tile, BK=32, 256 threads = 4 waves, each wave 64x64 via 4x4 of 16x16x32 MFMA.
// Staging via global_load_lds width=16 (m97 pattern).
template <typename OutT>
__global__ __launch_bounds__(256) void gemm_bt_kernel(const short* __restrict__ A,
                                                      const short* __restrict__ Bt,
                                                      OutT* __restrict__ C,
                                                      int M, int N, int K) {
  __shared__ short As[128 * 32];
  __shared__ short Bs[128 * 32];
  const int tid = threadIdx.x;
  const int lane = tid & 63, wave = tid >> 6;
  const int quad = lane >> 4, l16 = lane & 15;
  const int m0 = blockIdx.y * 128, n0 = blockIdx.x * 128;
  const int wm = (wave >> 1) * 64, wn = (wave & 1) * 64;

  f32x4 acc[4][4] = {};

  // global_load_lds staging: wave w, instr t in {0,1}:
  //   lds byte base = (w*2+t)*1024 (uniform); lane i -> row w*32+t*16+i/4, kcol (i&3)*8
  const int lrow = wave * 32 + (lane >> 2);
  const int lcol = (lane & 3) * 8;
  const short* ga0 = A + (size_t)(m0 + lrow) * K + lcol;
  const short* ga1 = A + (size_t)(m0 + lrow + 16) * K + lcol;
  const short* gb0 = Bt + (size_t)(n0 + lrow) * K + lcol;
  const short* gb1 = Bt + (size_t)(n0 + lrow + 16) * K + lcol;
  short* la0 = &As[(wave * 2 + 0) * 512];
  short* la1 = &As[(wave * 2 + 1) * 512];
  short* lb0 = &Bs[(wave * 2 + 0) * 512];
  short* lb1 = &Bs[(wave * 2 + 1) * 512];

  for (int kt = 0; kt < K; kt += 32) {
    __syncthreads();                 // prev iter's LDS reads done
    async_copy16(ga0 + kt, la0);
    async_copy16(ga1 + kt, la1);
    async_copy16(gb0 + kt, lb0);
    async_copy16(gb1 + kt, lb1);
    __syncthreads();                 // drains vmcnt(0): staged data visible
    bf16x8 af[4], bfr[4];
#pragma unroll
    for (int mt = 0; mt < 4; mt++)
      af[mt] = *(const bf16x8*)&As[(wm + mt * 16 + l16) * 32 + quad * 8];
#pragma unroll
    for (int nt = 0; nt < 4; nt++)
      bfr[nt] = *(const bf16x8*)&Bs[(wn + nt * 16 + l16) * 32 + quad * 8];
#pragma unroll
    for (int mt = 0; mt < 4; mt++)
#pragma unroll
      for (int nt = 0; nt < 4; nt++)
        acc[mt][nt] = __builtin_amdgcn_mfma_f32_16x16x32_bf16(af[mt], bfr[nt], acc[mt][nt], 0, 0, 0);
  }

#pragma unroll
  for (int mt = 0; mt < 4; mt++)
#pragma unroll
    for (int nt = 0; nt < 4; nt++) {
      const int col = n0 + wn + nt * 16 + l16;
#pragma unroll
      for (int r = 0; r < 4; r++) {
        const int row = m0 + wm + mt * 16 + quad * 4 + r;
        const float v = acc[mt][nt][r];
        if constexpr (sizeof(OutT) == 4) {
          C[(size_t)row * N + col] = v;
        } else {
          C[(size_t)row * N + col] = f2b(v);
        }
      }
    }
}

// ---------------- causal flash attention ----------------
// grid: (16, B*H), block 256. Block x handles qtiles {31-x, x} (uniform 33 KV-iters).
// Q pre-scaled by 1/sqrt(HD)*log2(e) (folded into w_attn); softmax in exp2 domain.
// Ks padded to stride 72 (unpadded 64 = exact 32-bank multiple -> 16-way conflicts).
// Row-sum of P computed by MFMA against all-ones B fragment (saves the shuffle reduce).
__global__ __launch_bounds__(256) void attn_kernel(const short* __restrict__ qkv,
                                                   short* __restrict__ y) {
  constexpr int T = 2048, C3 = 3072, Cc = 1024, HD = 64, NQ = 32;
  constexpr int KS = 72;             // Ks leading-dim pad: 2-way (free) frag reads
  const int bh = blockIdx.y, b = bh >> 4, h = bh & 15;
  const int tid = threadIdx.x, lane = tid & 63, wave = tid >> 6;
  const int quad = lane >> 4, l16 = lane & 15;

  __shared__ short Ks[64 * KS];      // [kv][d]
  __shared__ short Vt[64 * 72];      // [d][kv], pad +8
  __shared__ short Ps[4][16 * 72];   // per-wave P [q][kv], pad +8

  const size_t base = (size_t)b * T * C3;
  const int qcol = h * HD, kcol = Cc + h * HD, vcol = 2 * Cc + h * HD;
  const int srow = tid >> 2;        // 0..63
  const int sc0 = (tid & 3) * 16;   // 0,16,32,48

  bf16x8 ones;
#pragma unroll
  for (int i = 0; i < 8; i++) ones[i] = (short)0x3F80;  // bf16 1.0

  for (int half = 0; half < 2; half++) {
    const int qtile = half ? blockIdx.x : (NQ - 1 - blockIdx.x);
    const int q0 = qtile * 64;

    // Q fragments for this wave's 16 rows (A-layout: m=l16, k=quad*8+j)
    bf16x8 qf[2];
    {
      const short* qp = qkv + base + (size_t)(q0 + wave * 16 + l16) * C3 + qcol + quad * 8;
      qf[0] = *(const bf16x8*)qp;
      qf[1] = *(const bf16x8*)(qp + 32);
    }

    float m_r[4], l_r[4];
    f32x4 o[4] = {};
#pragma unroll
    for (int r = 0; r < 4; r++) { m_r[r] = -INFINITY; l_r[r] = 0.f; }

    for (int j = 0; j <= qtile; j++) {
      const int kv0 = j * 64;
      __syncthreads();   // all waves done reading Ks/Vt from previous iter
      {
        const short* kp = qkv + base + (size_t)(kv0 + srow) * C3 + kcol + sc0;
        *(bf16x8*)&Ks[srow * KS + sc0] = *(const bf16x8*)kp;
        *(bf16x8*)&Ks[srow * KS + sc0 + 8] = *(const bf16x8*)(kp + 8);
        const short* vp = qkv + base + (size_t)(kv0 + srow) * C3 + vcol + sc0;
        bf16x8 v0 = *(const bf16x8*)vp;
        bf16x8 v1 = *(const bf16x8*)(vp + 8);
#pragma unroll
        for (int jj = 0; jj < 8; jj++) {
          Vt[(sc0 + jj) * 72 + srow] = v0[jj];
          Vt[(sc0 + 8 + jj) * 72 + srow] = v1[jj];
        }
      }
      __syncthreads();

      // S = Q * K^T  (16 x 64 per wave), already in log2 units
      f32x4 s[4];
#pragma unroll
      for (int nt = 0; nt < 4; nt++) {
        bf16x8 b0 = *(const bf16x8*)&Ks[(nt * 16 + l16) * KS + quad * 8];
        bf16x8 b1 = *(const bf16x8*)&Ks[(nt * 16 + l16) * KS + 32 + quad * 8];
        f32x4 a = {};
        a = __builtin_amdgcn_mfma_f32_16x16x32_bf16(qf[0], b0, a, 0, 0, 0);
        a = __builtin_amdgcn_mfma_f32_16x16x32_bf16(qf[1], b1, a, 0, 0, 0);
        s[nt] = a;
      }

      const bool diag = (j == qtile);
      float rowmax[4];
#pragma unroll
      for (int r = 0; r < 4; r++) rowmax[r] = -INFINITY;
      if (diag) {
#pragma unroll
        for (int nt = 0; nt < 4; nt++)
#pragma unroll
          for (int r = 0; r < 4; r++) {
            const int row_l = wave * 16 + quad * 4 + r;
            const int col_l = nt * 16 + l16;
            if (col_l > row_l) s[nt][r] = -INFINITY;
            rowmax[r] = fmaxf(rowmax[r], s[nt][r]);
          }
      } else {
#pragma unroll
        for (int nt = 0; nt < 4; nt++)
#pragma unroll
          for (int r = 0; r < 4; r++)
            rowmax[r] = fmaxf(rowmax[r], s[nt][r]);
      }
#pragma unroll
      for (int r = 0; r < 4; r++)
#pragma unroll
        for (int off = 1; off < 16; off <<= 1)
          rowmax[r] = fmaxf(rowmax[r], __shfl_xor(rowmax[r], off));

      float alpha[4];
#pragma unroll
      for (int r = 0; r < 4; r++) {
        const float mn = fmaxf(m_r[r], rowmax[r]);
        alpha[r] = __builtin_amdgcn_exp2f(m_r[r] - mn);
        m_r[r] = mn;
      }
#pragma unroll
      for (int nt = 0; nt < 4; nt++)
#pragma unroll
        for (int r = 0; r < 4; r++)
          s[nt][r] = __builtin_amdgcn_exp2f(s[nt][r] - m_r[r]);
#pragma unroll
      for (int nt = 0; nt < 4; nt++)
#pragma unroll
        for (int r = 0; r < 4; r++)
          o[nt][r] *= alpha[r];

      // P: C-layout regs -> LDS -> A-layout frags. Ps[wave] is wave-private, but
      // LDS ops complete out of order: wave-local lgkmcnt drain before the reads.
#pragma unroll
      for (int nt = 0; nt < 4; nt++)
#pragma unroll
        for (int r = 0; r < 4; r++)
          Ps[wave][(quad * 4 + r) * 72 + nt * 16 + l16] = f2b(s[nt][r]);
      asm volatile("s_waitcnt lgkmcnt(0)" ::: "memory");

      bf16x8 pa0 = *(const bf16x8*)&Ps[wave][l16 * 72 + quad * 8];
      bf16x8 pa1 = *(const bf16x8*)&Ps[wave][l16 * 72 + 32 + quad * 8];

      // row-sum of P via MFMA with ones-B: D[row=quad*4+r][*] = sum_kv P[row][kv]
      f32x4 lsum = {};
      lsum = __builtin_amdgcn_mfma_f32_16x16x32_bf16(pa0, ones, lsum, 0, 0, 0);
      lsum = __builtin_amdgcn_mfma_f32_16x16x32_bf16(pa1, ones, lsum, 0, 0, 0);
#pragma unroll
      for (int r = 0; r < 4; r++)
        l_r[r] = l_r[r] * alpha[r] + lsum[r];

#pragma unroll
      for (int nt = 0; nt < 4; nt++) {
        bf16x8 vb0 = *(const bf16x8*)&Vt[(nt * 16 + l16) * 72 + quad * 8];
        o[nt] = __builtin_amdgcn_mfma_f32_16x16x32_bf16(pa0, vb0, o[nt], 0, 0, 0);
        bf16x8 vb1 = *(const bf16x8*)&Vt[(nt * 16 + l16) * 72 + 32 + quad * 8];
        o[nt] = __builtin_amdgcn_mfma_f32_16x16x32_bf16(pa1, vb1, o[nt], 0, 0, 0);
      }
    }

#pragma unroll
    for (int nt = 0; nt < 4; nt++)
#pragma unroll
      for (int r = 0; r < 4; r++) {
        const int row_g = q0 + wave * 16 + quad * 4 + r;
        y[(size_t)(b * T + row_g) * Cc + h * HD + nt * 16 + l16] = f2b(o[nt][r] / l_r[r]);
      }
  }
}

extern "C" void kernel_launch(void* const* d_in, const int* in_sizes, int n_in,
                              void* d_out, int out_size, void* d_ws, size_t ws_size,
                              hipStream_t stream) {
  constexpr int B = 4, T = 2048, C = 1024;
  constexpr int M = B * T;          // 8192
  constexpr int N1 = 3 * C;         // 3072
  const float* x      = (const float*)d_in[0];
  const float* w_attn = (const float*)d_in[1];
  const float* w_proj = (const float*)d_in[2];
  float* out = (float*)d_out;

  char* ws = (char*)d_ws;
  short* xb   = (short*)(ws + 0);                       // 8192*1024   = 16 MB
  short* waT  = (short*)(ws + 16777216);                // 3072*1024   =  6 MB
  short* wpT  = (short*)(ws + 23068672);                // 1024*1024   =  2 MB
  short* qkvb = (short*)(ws + 25165824);                // 8192*3072   = 48 MB
  short* yb   = (short*)(ws + 75497472);                // 8192*1024   = 16 MB

  // softmax scale folded into Q columns: 1/sqrt(64) * log2(e)
  const float qscale = 0.125f * 1.44269504088896340736f;

  cvt_kernel<<<(M * C / 4 + 255) / 256, 256, 0, stream>>>(x, xb, M * C / 4);
  tcvt_kernel<<<dim3(N1 / 32, C / 32), dim3(32, 8), 0, stream>>>(w_attn, waT, C, N1, C, qscale);
  tcvt_kernel<<<dim3(C / 32, C / 32), dim3(32, 8), 0, stream>>>(w_proj, wpT, C, C, 0, 1.0f);
  gemm_bt_kernel<short><<<dim3(N1 / 128, M / 128), 256, 0, stream>>>(xb, waT, qkvb, M, N1, C);
  attn_kernel<<<dim3(16, B * 16), 256, 0, stream>>>(qkvb, yb);
  gemm_bt_kernel<float><<<dim3(C / 128, M / 128), 256, 0, stream>>>(yb, wpT, out, M, C, C);
}